// Round 5
// baseline (35547.861 us; speedup 1.0000x reference)
//
#include <hip/hip_runtime.h>
#include <hip/hip_fp16.h>
#include <math.h>

#define EPS 1e-5f

typedef _Float16 h8_t __attribute__((ext_vector_type(8)));
typedef float fx4_t __attribute__((ext_vector_type(4)));

__device__ __forceinline__ float sgnf(float w) {
    return (w > 0.f) ? 1.f : ((w < 0.f) ? -1.f : 0.f);
}

// ======================= PROVEN R2 PATH (owns d_out) =======================

template<int CI, bool POOL>
__global__ void conv_bn_relu_kernel(
    const float* __restrict__ x, const float* __restrict__ w,
    const float* __restrict__ bias, const float* __restrict__ g,
    const float* __restrict__ be, const float* __restrict__ m,
    const float* __restrict__ v,
    float* __restrict__ y,
    int B, int CO, int IH, int IW)
{
    const int OH = IH - 2, OW = IW - 2;
    const int PH = POOL ? OH / 2 : OH;
    const int PW = POOL ? OW / 2 : OW;

    long long idx = (long long)blockIdx.x * blockDim.x + threadIdx.x;
    long long total = (long long)B * CO * PH * PW;
    if (idx >= total) return;

    int pw = (int)(idx % PW); long long t = idx / PW;
    int ph = (int)(t % PH); t /= PH;
    int co = (int)(t % CO);
    int b  = (int)(t / CO);

    float scale = g[co] * rsqrtf(v[co] + EPS);
    float shift = be[co] - m[co] * scale + bias[co] * scale;

    const float* wp = w + (long long)co * CI * 9;
    const float* xb = x + (long long)b * CI * IH * IW;

    float result = 0.f;
    #pragma unroll
    for (int dy = 0; dy < (POOL ? 2 : 1); ++dy) {
        #pragma unroll
        for (int dx = 0; dx < (POOL ? 2 : 1); ++dx) {
            const int oh = POOL ? (2 * ph + dy) : ph;
            const int ow = POOL ? (2 * pw + dx) : pw;
            float acc = 0.f;
            #pragma unroll 2
            for (int ci = 0; ci < CI; ++ci) {
                const float* xp = xb + ((long long)ci * IH + oh) * IW + ow;
                const float* wq = wp + ci * 9;
                #pragma unroll
                for (int kh = 0; kh < 3; ++kh) {
                    #pragma unroll
                    for (int kw = 0; kw < 3; ++kw) {
                        acc += xp[kh * IW + kw] * sgnf(wq[kh * 3 + kw]);
                    }
                }
            }
            float val = fmaxf(acc * scale + shift, 0.f);
            if (dy == 0 && dx == 0) result = val;
            else result = fmaxf(result, val);
        }
    }
    y[idx] = result;
}

__global__ void fc_kernel(const float* __restrict__ x, const float* __restrict__ w,
                          const float* __restrict__ bias, float* __restrict__ y,
                          int B, int IN, int OUT, int do_relu)
{
    int idx = blockIdx.x * blockDim.x + threadIdx.x;
    if (idx >= B * OUT) return;
    int o = idx % OUT, b = idx / OUT;
    const float* xp = x + (long long)b * IN;
    const float* wp = w + (long long)o * IN;
    float acc = bias[o];
    #pragma unroll 4
    for (int k = 0; k < IN; ++k) acc += xp[k] * sgnf(wp[k]);
    y[idx] = do_relu ? fmaxf(acc, 0.f) : acc;
}

__global__ void softmax10_kernel(const float* __restrict__ logits,
                                 float* __restrict__ out, int B)
{
    int b = blockIdx.x * blockDim.x + threadIdx.x;
    if (b >= B) return;
    float l[10];
    float mx = -1e30f;
    #pragma unroll
    for (int i = 0; i < 10; ++i) { l[i] = logits[b * 10 + i]; mx = fmaxf(mx, l[i]); }
    float s = 0.f;
    #pragma unroll
    for (int i = 0; i < 10; ++i) { l[i] = __expf(l[i] - mx); s += l[i]; }
    float r = 1.f / s;
    #pragma unroll
    for (int i = 0; i < 10; ++i) out[b * 10 + i] = l[i] * r;
}

// ================= PROBE KERNELS (write dead scratch only) =================

__global__ void bnfold_kernel(const float* __restrict__ g, const float* __restrict__ be,
                              const float* __restrict__ m, const float* __restrict__ v,
                              const float* __restrict__ bias,
                              float* __restrict__ sc, float* __restrict__ sh, int CO) {
    int i = blockIdx.x * blockDim.x + threadIdx.x;
    if (i >= CO) return;
    float s = g[i] * rsqrtf(v[i] + EPS);
    sc[i] = s;
    sh[i] = be[i] + (bias[i] - m[i]) * s;
}

__global__ void packw_kernel(const float* __restrict__ w, _Float16* __restrict__ wp,
                             int CO, int CI) {
    int idx = blockIdx.x * blockDim.x + threadIdx.x;
    if (idx >= CO * CI * 9) return;
    int ci = idx % CI; int t = idx / CI;
    int khw = t % 9; int co = t / 9;
    wp[idx] = (_Float16)sgnf(w[((long)co * CI + ci) * 9 + khw]);
}

__global__ __launch_bounds__(256) void conv1_kernel(
    const float* __restrict__ x, const float* __restrict__ w,
    const float* __restrict__ sc, const float* __restrict__ sh,
    _Float16* __restrict__ y) {
    __shared__ float sw[27 * 128];
    int tid = threadIdx.x;
    for (int i = tid; i < 27 * 128; i += 256) {
        int k = i >> 7, co = i & 127;
        int ci = k % 3, khw = k / 3;
        sw[i] = sgnf(w[(co * 3 + ci) * 9 + khw]);
    }
    __syncthreads();
    int g = tid & 15, mi = tid >> 4;
    int m = blockIdx.x * 16 + mi;
    int b = m / 900, rem = m % 900;
    int oh = rem / 30, ow = rem % 30;
    const float* xb = x + (long)b * 3 * 1024;
    float xv[27];
    #pragma unroll
    for (int ci = 0; ci < 3; ++ci)
        #pragma unroll
        for (int r = 0; r < 3; ++r)
            #pragma unroll
            for (int c = 0; c < 3; ++c)
                xv[(r * 3 + c) * 3 + ci] = xb[ci * 1024 + (oh + r) * 32 + (ow + c)];
    float acc[8] = {0.f, 0.f, 0.f, 0.f, 0.f, 0.f, 0.f, 0.f};
    const float* swg = sw + g * 8;
    #pragma unroll
    for (int k = 0; k < 27; ++k) {
        float xk = xv[k];
        #pragma unroll
        for (int j = 0; j < 8; ++j) acc[j] = fmaf(xk, swg[k * 128 + j], acc[j]);
    }
    h8_t o;
    #pragma unroll
    for (int j = 0; j < 8; ++j) {
        int co = g * 8 + j;
        o[j] = (_Float16)fmaxf(acc[j] * sc[co] + sh[co], 0.f);
    }
    *(h8_t*)(y + (long)m * 128 + g * 8) = o;
}

template <typename OutT>
__global__ __launch_bounds__(256) void gemm_conv_kernel(
    const _Float16* __restrict__ x, const _Float16* __restrict__ wp,
    const float* __restrict__ sc, const float* __restrict__ sh,
    OutT* __restrict__ y,
    int N, int K9, int CI, int IH, int IW, int OH, int OW) {
    __shared__ _Float16 As[128 * 72];
    __shared__ _Float16 Bs[128 * 72];
    const int tid = threadIdx.x;
    const int lane = tid & 63, w = tid >> 6;
    const int wm = w & 1, wn = w >> 1;
    const int m0 = blockIdx.x * 128, n0 = blockIdx.y * 128;

    const int scol = (lane & 7) * 8;
    const int srl = lane >> 3;
    long baseA[4];
    int baseB[4], ldsrow[4];
    #pragma unroll
    for (int i = 0; i < 4; ++i) {
        int r = w * 32 + i * 8 + srl;
        ldsrow[i] = r;
        int m = m0 + r;
        int b = m / (OH * OW); int rm = m - b * (OH * OW);
        int oh = rm / OW; int ow = rm - oh * OW;
        baseA[i] = (((long)b * IH + oh) * IW + ow) * CI + scol;
        baseB[i] = (n0 + r) * K9 + scol;
    }

    fx4_t acc[4][4];
    #pragma unroll
    for (int a = 0; a < 4; ++a)
        #pragma unroll
        for (int bq = 0; bq < 4; ++bq)
            #pragma unroll
            for (int e = 0; e < 4; ++e) acc[a][bq][e] = 0.f;

    const int nkt = K9 >> 6;
    for (int kt = 0; kt < nkt; ++kt) {
        const int k0 = kt << 6;
        const int t9 = k0 / CI;
        const int kh = t9 / 3, kw = t9 - kh * 3;
        const int ci0 = k0 - t9 * CI;
        const long koffA = ((long)kh * IW + kw) * CI + ci0;
        uint4 ra[4], rb[4];
        #pragma unroll
        for (int i = 0; i < 4; ++i) {
            ra[i] = *(const uint4*)(x + baseA[i] + koffA);
            rb[i] = *(const uint4*)(wp + baseB[i] + k0);
        }
        __syncthreads();
        #pragma unroll
        for (int i = 0; i < 4; ++i) {
            *(uint4*)(As + ldsrow[i] * 72 + scol) = ra[i];
            *(uint4*)(Bs + ldsrow[i] * 72 + scol) = rb[i];
        }
        __syncthreads();
        #pragma unroll
        for (int kk = 0; kk < 2; ++kk) {
            const int kb = kk * 32 + (lane >> 4) * 8;
            h8_t af[4], bf[4];
            #pragma unroll
            for (int mf = 0; mf < 4; ++mf)
                af[mf] = *(const h8_t*)(As + (wm * 64 + mf * 16 + (lane & 15)) * 72 + kb);
            #pragma unroll
            for (int nf = 0; nf < 4; ++nf)
                bf[nf] = *(const h8_t*)(Bs + (wn * 64 + nf * 16 + (lane & 15)) * 72 + kb);
            #pragma unroll
            for (int mf = 0; mf < 4; ++mf)
                #pragma unroll
                for (int nf = 0; nf < 4; ++nf)
                    acc[mf][nf] = __builtin_amdgcn_mfma_f32_16x16x32_f16(
                        af[mf], bf[nf], acc[mf][nf], 0, 0, 0);
        }
    }

    const int col = lane & 15, row4 = (lane >> 4) * 4;
    #pragma unroll
    for (int nf = 0; nf < 4; ++nf) {
        int n = n0 + wn * 64 + nf * 16 + col;
        float s = sc[n], h = sh[n];
        #pragma unroll
        for (int mf = 0; mf < 4; ++mf)
            #pragma unroll
            for (int reg = 0; reg < 4; ++reg) {
                int m = m0 + wm * 64 + mf * 16 + row4 + reg;
                float vv = fmaxf(acc[mf][nf][reg] * s + h, 0.f);
                y[(long)m * N + n] = (OutT)vv;
            }
    }
}

template <typename OutT>
__global__ void gemm_ref_kernel(const _Float16* __restrict__ x, const _Float16* __restrict__ wp,
                                const float* __restrict__ sc, const float* __restrict__ sh,
                                OutT* __restrict__ y,
                                long M, int N, int CI, int IH, int IW, int OH, int OW) {
    long idx = (long)blockIdx.x * blockDim.x + threadIdx.x;
    if (idx >= M * (long)N) return;
    int n = (int)(idx % N); long m = idx / N;
    int b = (int)(m / (OH * OW)); int rm = (int)(m % (OH * OW));
    int oh = rm / OW, ow = rm % OW;
    const int K9 = 9 * CI;
    float acc = 0.f;
    for (int khw = 0; khw < 9; ++khw) {
        int kh = khw / 3, kw = khw % 3;
        const _Float16* xp = x + (((long)b * IH + oh + kh) * IW + (ow + kw)) * CI;
        const _Float16* wq = wp + (long)n * K9 + khw * CI;
        for (int ci = 0; ci < CI; ci += 2)
            acc += (float)xp[ci] * (float)wq[ci] + (float)xp[ci + 1] * (float)wq[ci + 1];
    }
    y[m * (long)N + n] = (OutT)fmaxf(acc * sc[n] + sh[n], 0.f);
}

__global__ void pool_kernel(const _Float16* __restrict__ in, _Float16* __restrict__ out,
                            int B, int H, int W, int C) {
    int PH = H / 2, PW = W / 2, C8 = C / 8;
    long total = (long)B * PH * PW * C8;
    long idx = (long)blockIdx.x * blockDim.x + threadIdx.x;
    if (idx >= total) return;
    int c8 = (int)(idx % C8); long t = idx / C8;
    int pw = (int)(t % PW); t /= PW;
    int ph = (int)(t % PH); int b = (int)(t / PH);
    const _Float16* p = in + (((long)b * H + 2 * ph) * W + 2 * pw) * C + c8 * 8;
    h8_t a = *(const h8_t*)p;
    h8_t b2 = *(const h8_t*)(p + C);
    h8_t c = *(const h8_t*)(p + (long)W * C);
    h8_t d = *(const h8_t*)(p + (long)W * C + C);
    h8_t o;
    #pragma unroll
    for (int j = 0; j < 8; ++j) {
        _Float16 m1 = a[j] > b2[j] ? a[j] : b2[j];
        _Float16 m2 = c[j] > d[j] ? c[j] : d[j];
        o[j] = m1 > m2 ? m1 : m2;
    }
    *(h8_t*)(out + idx * 8) = o;
}

static inline int cdiv_ll(long long a, int b) { return (int)((a + b - 1) / b); }

extern "C" void kernel_launch(void* const* d_in, const int* in_sizes, int n_in,
                              void* d_out, int out_size, void* d_ws, size_t ws_size,
                              hipStream_t stream) {
    const int B = 512;
    const float* x = (const float*)d_in[0];
    auto W  = [&](int i) { return (const float*)d_in[1 + (i - 1) * 6 + 0]; };
    auto Bi = [&](int i) { return (const float*)d_in[1 + (i - 1) * 6 + 1]; };
    auto G  = [&](int i) { return (const float*)d_in[1 + (i - 1) * 6 + 2]; };
    auto Be = [&](int i) { return (const float*)d_in[1 + (i - 1) * 6 + 3]; };
    auto M  = [&](int i) { return (const float*)d_in[1 + (i - 1) * 6 + 4]; };
    auto V  = [&](int i) { return (const float*)d_in[1 + (i - 1) * 6 + 5]; };
    const float* fw1 = (const float*)d_in[37];
    const float* fb1 = (const float*)d_in[38];
    const float* fw2 = (const float*)d_in[39];
    const float* fb2 = (const float*)d_in[40];
    const float* fw3 = (const float*)d_in[41];
    const float* fb3 = (const float*)d_in[42];
    float* out = (float*)d_out;

    // ---- proven R2 path, chunked; Bc capped at 128 (71.8 MB) to leave probe room ----
    const long long B0_PER = 115200, B1_PER = 25088;
    const long long need_per_b = (B0_PER + B1_PER) * (long long)sizeof(float);
    int Bc = B;
    while (Bc > 1 && (long long)Bc * need_per_b > (long long)ws_size) Bc >>= 1;
    if (Bc > 128) Bc = 128;

    const int TB = 256;

    for (int b0 = 0; b0 < B; b0 += Bc) {
        float* buf0 = (float*)d_ws;
        float* buf1 = buf0 + (long long)Bc * B0_PER;
        const float* xc = x + (long long)b0 * 3 * 32 * 32;
        long long n;

        n = (long long)Bc * 128 * 30 * 30;
        conv_bn_relu_kernel<3, false><<<cdiv_ll(n, TB), TB, 0, stream>>>(
            xc, W(1), Bi(1), G(1), Be(1), M(1), V(1), buf0, Bc, 128, 32, 32);

        n = (long long)Bc * 128 * 14 * 14;
        conv_bn_relu_kernel<128, true><<<cdiv_ll(n, TB), TB, 0, stream>>>(
            buf0, W(2), Bi(2), G(2), Be(2), M(2), V(2), buf1, Bc, 128, 30, 30);

        n = (long long)Bc * 256 * 12 * 12;
        conv_bn_relu_kernel<128, false><<<cdiv_ll(n, TB), TB, 0, stream>>>(
            buf1, W(3), Bi(3), G(3), Be(3), M(3), V(3), buf0, Bc, 256, 14, 14);

        n = (long long)Bc * 256 * 5 * 5;
        conv_bn_relu_kernel<256, true><<<cdiv_ll(n, TB), TB, 0, stream>>>(
            buf0, W(4), Bi(4), G(4), Be(4), M(4), V(4), buf1, Bc, 256, 12, 12);

        n = (long long)Bc * 512 * 3 * 3;
        conv_bn_relu_kernel<256, false><<<cdiv_ll(n, TB), TB, 0, stream>>>(
            buf1, W(5), Bi(5), G(5), Be(5), M(5), V(5), buf0, Bc, 512, 5, 5);

        n = (long long)Bc * 512 * 1 * 1;
        conv_bn_relu_kernel<512, false><<<cdiv_ll(n, TB), TB, 0, stream>>>(
            buf0, W(6), Bi(6), G(6), Be(6), M(6), V(6), buf1, Bc, 512, 3, 3);

        n = (long long)Bc * 1024;
        fc_kernel<<<cdiv_ll(n, TB), TB, 0, stream>>>(buf1, fw1, fb1, buf0, Bc, 512, 1024, 1);
        fc_kernel<<<cdiv_ll(n, TB), TB, 0, stream>>>(buf0, fw2, fb2, buf1, Bc, 1024, 1024, 1);
        n = (long long)Bc * 10;
        fc_kernel<<<cdiv_ll(n, TB), TB, 0, stream>>>(buf1, fw3, fb3, buf0, Bc, 1024, 10, 0);

        softmax10_kernel<<<cdiv_ll(Bc, TB), TB, 0, stream>>>(buf0, out + (long long)b0 * 10, Bc);
    }

    // ---- probes: exercise every NEW kernel incl. one MFMA tile, dead scratch ----
    // R2 proved ws_size >= 143.6 MB (Bc=256 fit); probes live at +120 MB, ~4 MB used.
    if (ws_size >= (size_t)135 << 20) {
        char* pbase = (char*)d_ws + ((size_t)120 << 20);
        float*    psc  = (float*)pbase;                      // 128 f32
        float*    psh  = psc + 128;                          // 128 f32
        _Float16* pwp  = (_Float16*)(psh + 128);             // 128*128*9 f16 = 294912 B
        _Float16* pA   = pwp + 147456;                       // 1M f16 = 2 MB (poison in)
        _Float16* pOut = pA + 1048576;                       // 16384 f16
        _Float16* pC1  = pOut + 16384;                       // 2048 f16
        _Float16* pPool= pC1 + 2048;                         // 25088 f16

        bnfold_kernel<<<1, TB, 0, stream>>>(G(2), Be(2), M(2), V(2), Bi(2), psc, psh, 128);
        packw_kernel<<<cdiv_ll(128 * 128 * 9, TB), TB, 0, stream>>>(W(2), pwp, 128, 128);
        conv1_kernel<<<1, TB, 0, stream>>>(x, W(1), psc, psh, pC1);
        // MFMA probe: one 128x128 tile, K9=1152, reads pA (poison ok), writes pOut
        gemm_conv_kernel<_Float16><<<dim3(1, 1), TB, 0, stream>>>(
            pA, pwp, psc, psh, pOut, 128, 1152, 128, 30, 30, 28, 28);
        gemm_ref_kernel<_Float16><<<cdiv_ll(128 * 128, TB), TB, 0, stream>>>(
            pA, pwp, psc, psh, pOut, 128, 128, 128, 30, 30, 28, 28);
        pool_kernel<<<cdiv_ll(1 * 14 * 14 * 16, TB), TB, 0, stream>>>(pA, pPool, 1, 28, 28, 128);
    }
}